// Round 7
// baseline (244.858 us; speedup 1.0000x reference)
//
#include <hip/hip_runtime.h>

// ---------------- types ----------------
typedef __bf16 bf16x8 __attribute__((ext_vector_type(8)));
typedef float  f32x4  __attribute__((ext_vector_type(4)));
typedef unsigned short ushort8 __attribute__((ext_vector_type(8)));

#define B_ROWS 8192
#define OUT_D  512
#define O2C_D  256
#define TOT_D  768
#define MIN_D  768
#define RNN_D  1024

__device__ __forceinline__ unsigned short f2bf(float f) {
    unsigned int u = __builtin_bit_cast(unsigned int, f);
    u = (u + 0x7fff + ((u >> 16) & 1)) >> 16;   // RNE
    return (unsigned short)u;
}

__device__ __forceinline__ void load_lds16(const void* g, void* l) {
    __builtin_amdgcn_global_load_lds(
        (const __attribute__((address_space(1))) unsigned int*)g,
        (__attribute__((address_space(3))) unsigned int*)l, 16, 0, 0);
}

// ---------------- fused prep kernel ----------------
// blockIdx segments: [0,128) reduce_sq partials; [128,1984) weight cvt; [1984,10176) act cvt
__launch_bounds__(256)
__global__ void prep_all(const float* __restrict__ Wread, float* __restrict__ partials,
                         const float* __restrict__ Wpre, const float* __restrict__ Wx,
                         const float* __restrict__ Wh,  const float* __restrict__ Wpost,
                         unsigned short* __restrict__ WpreT, unsigned short* __restrict__ WxhT,
                         unsigned short* __restrict__ WpostT, unsigned short* __restrict__ WreadT,
                         const float* __restrict__ center, const float* __restrict__ inputs,
                         const float* __restrict__ mstate,
                         unsigned short* __restrict__ csB, unsigned short* __restrict__ miB,
                         unsigned short* __restrict__ rnB) {
    const int bid = blockIdx.x;
    const int tid = threadIdx.x;
    if (bid < 128) {
        __shared__ float red[4];
        const float* p = Wread + bid * 1024 + tid * 4;
        f32x4 v = *(const f32x4*)p;
        float s = v[0]*v[0] + v[1]*v[1] + v[2]*v[2] + v[3]*v[3];
        #pragma unroll
        for (int off = 32; off > 0; off >>= 1) s += __shfl_down(s, off, 64);
        if ((tid & 63) == 0) red[tid >> 6] = s;
        __syncthreads();
        if (tid == 0) partials[bid] = red[0] + red[1] + red[2] + red[3];
        return;
    }
    if (bid < 1984) {
        int g = (bid - 128) * 256 + tid;
        const float* W; unsigned short* out; int N, ostride;
        if (g < 98304)        { W = Wpre;  out = WpreT;        N = 1024; ostride = 768;  }
        else if (g < 229376)  { g -= 98304;  W = Wx;    out = WxhT;        N = 1024; ostride = 2048; }
        else if (g < 360448)  { g -= 229376; W = Wh;    out = WxhT + 1024; N = 1024; ostride = 2048; }
        else if (g < 458752)  { g -= 360448; W = Wpost; out = WpostT;      N = 768;  ostride = 1024; }
        else                  { g -= 458752; W = Wread; out = WreadT;      N = 256;  ostride = 512;  }
        int n  = g % N;
        int kg = g / N;
        ushort8 o;
        #pragma unroll
        for (int j = 0; j < 8; ++j)
            o[j] = f2bf(W[(long)(kg * 8 + j) * N + n]);
        *(ushort8*)(out + (long)n * ostride + kg * 8) = o;
        return;
    }
    long g = (long)(bid - 1984) * 256 + tid;
    const float* src; unsigned short* dst; int logc, ostride;
    if (g < 524288)       { src = center; dst = csB;        logc = 9;  ostride = 512;  }
    else if (g < 1048576) { g -= 524288;  src = inputs; dst = miB;        logc = 9;  ostride = 768;  }
    else                  { g -= 1048576; src = mstate; dst = rnB + 1024; logc = 10; ostride = 2048; }
    long e = g * 8;
    long row = e >> logc;
    int  col = (int)(e & ((1 << logc) - 1));
    f32x4 v0 = *(const f32x4*)(src + e);
    f32x4 v1 = *(const f32x4*)(src + e + 4);
    ushort8 o;
    o[0] = f2bf(v0[0]); o[1] = f2bf(v0[1]); o[2] = f2bf(v0[2]); o[3] = f2bf(v0[3]);
    o[4] = f2bf(v1[0]); o[5] = f2bf(v1[1]); o[6] = f2bf(v1[2]); o[7] = f2bf(v1[3]);
    *(ushort8*)(dst + row * (long)ostride + col) = o;
}

// ---------------- small GEMM (single-buffer, round-0 proven) — used for L1 ----------------
// BM=128, BNT=64, BK=64. 4 waves. Conflict-free swizzle (verified r2/r6).
// MODE 0: *clipscale (bias = 128 partials of sum(W_read^2)) -> bf16
template<int MODE, int BNT>
__launch_bounds__(256, 4)
__global__ void gemm_bt(const unsigned short* __restrict__ A,
                        const unsigned short* __restrict__ Bt,
                        int K, const float* __restrict__ bias,
                        unsigned short* __restrict__ outB, int ldob,
                        float* __restrict__ outF, int ldof) {
    constexpr int U   = BNT / 32;
    constexpr int BJ  = BNT / 32;
    __shared__ alignas(16) unsigned short smem[128 * 64 + BNT * 64];
    unsigned short* sA = smem;
    unsigned short* sB = smem + 128 * 64;

    const int tid  = threadIdx.x;
    const int wave = tid >> 6;
    const int lane = tid & 63;
    const int bm = blockIdx.x, bn = blockIdx.y;
    const int wm = wave & 1, wn = wave >> 1;
    const int lr = lane >> 4;
    const int lc = lane & 15;
    const int sw = lc & 7;

    f32x4 acc[4][U] = {};

    long aoff[4], boff[BJ];
    #pragma unroll
    for (int j = 0; j < 4; ++j) {
        const int c   = tid + j * 256;
        const int row = c >> 3;
        const int kg  = (c & 7) ^ (row & 7);
        aoff[j] = (long)(bm * 128 + row) * K + kg * 8;
    }
    #pragma unroll
    for (int j = 0; j < BJ; ++j) {
        const int c   = tid + j * 256;
        const int row = c >> 3;
        const int kg  = (c & 7) ^ (row & 7);
        boff[j] = (long)(bn * BNT + row) * K + kg * 8;
    }

    for (int k0 = 0; k0 < K; k0 += 64) {
        #pragma unroll
        for (int j = 0; j < 4; ++j)
            load_lds16(A + aoff[j] + k0, (char*)sA + j * 4096 + wave * 1024);
        #pragma unroll
        for (int j = 0; j < BJ; ++j)
            load_lds16(Bt + boff[j] + k0, (char*)sB + j * 4096 + wave * 1024);
        __syncthreads();

        #pragma unroll
        for (int kh = 0; kh < 2; ++kh) {
            const int ch = (kh * 4 + lr) ^ sw;
            bf16x8 af[4], bfr[U];
            #pragma unroll
            for (int t = 0; t < 4; ++t)
                af[t] = *(const bf16x8*)(sA + (wm * 64 + t * 16 + lc) * 64 + ch * 8);
            #pragma unroll
            for (int u = 0; u < U; ++u)
                bfr[u] = *(const bf16x8*)(sB + (wn * (BNT / 2) + u * 16 + lc) * 64 + ch * 8);
            #pragma unroll
            for (int i = 0; i < 4; ++i)
                #pragma unroll
                for (int u = 0; u < U; ++u)
                    acc[i][u] = __builtin_amdgcn_mfma_f32_16x16x32_bf16(af[i], bfr[u], acc[i][u], 0, 0, 0);
        }
        __syncthreads();
    }

    float sc = 1.f;
    if constexpr (MODE == 0) {
        float s = 0.f;
        for (int i = 0; i < 128; ++i) s += bias[i];
        sc = 1.f / fmaxf(sqrtf(s), 1.f);
    }
    #pragma unroll
    for (int u = 0; u < U; ++u) {
        float bv = 0.f;
        if constexpr (MODE != 0) bv = bias[bn * BNT + wn * (BNT / 2) + u * 16 + lc];
        #pragma unroll
        for (int tm = 0; tm < 4; ++tm)
            #pragma unroll
            for (int r = 0; r < 4; ++r) {
                float v = acc[tm][u][r];
                if constexpr (MODE == 0) v *= sc;
                else v += bv;
                if constexpr (MODE == 1 || MODE == 3) v = fmaxf(v, 0.f);
                acc[tm][u][r] = v;
            }
    }

    const int ctcol = wn * (BNT / 2);

    if constexpr (MODE <= 2) {
        unsigned short* Cb = smem;
        #pragma unroll
        for (int u = 0; u < U; ++u)
            #pragma unroll
            for (int tm = 0; tm < 4; ++tm)
                #pragma unroll
                for (int r = 0; r < 4; ++r)
                    Cb[(wm * 64 + tm * 16 + lr * 4 + r) * BNT + ctcol + u * 16 + lc] =
                        f2bf(acc[tm][u][r]);
        __syncthreads();
        constexpr int RC = BNT / 8;
        constexpr int CPT = 128 * RC / 256;
        #pragma unroll
        for (int t = 0; t < CPT; ++t) {
            const int chunk = t * 256 + tid;
            const int row = chunk / RC;
            const int c8  = chunk % RC;
            ushort8 val = *(ushort8*)(Cb + row * BNT + c8 * 8);
            *(ushort8*)(outB + (long)(bm * 128 + row) * ldob + bn * BNT + c8 * 8) = val;
        }
    }

    if constexpr (MODE == 3) {
        float* Cf = (float*)smem;
        #pragma unroll
        for (int h = 0; h < 2; ++h) {
            __syncthreads();
            if (wm == h) {
                #pragma unroll
                for (int u = 0; u < U; ++u)
                    #pragma unroll
                    for (int tm = 0; tm < 4; ++tm)
                        #pragma unroll
                        for (int r = 0; r < 4; ++r)
                            Cf[(tm * 16 + lr * 4 + r) * BNT + ctcol + u * 16 + lc] =
                                acc[tm][u][r];
            }
            __syncthreads();
            constexpr int RCF = BNT / 4;
            constexpr int CPTF = 64 * RCF / 256;
            #pragma unroll
            for (int t = 0; t < CPTF; ++t) {
                const int chunk = t * 256 + tid;
                const int row = chunk / RCF;
                const int c4  = chunk % RCF;
                f32x4 val = *(f32x4*)(Cf + row * BNT + c4 * 4);
                const long grow = bm * 128 + h * 64 + row;
                if (bn * BNT < OUT_D)
                    *(f32x4*)(outF + grow * OUT_D + bn * BNT + c4 * 4) = val;
                else
                    *(f32x4*)(outF + (long)B_ROWS * OUT_D + grow * O2C_D
                              + (bn * BNT - OUT_D) + c4 * 4) = val;
            }
        }
    }
}

// ---------------- big GEMM: 256x128, tri-buffer, R4 schedule + R5 XCD remap ----------------
// 8 waves (4M x 2N), per-wave 64x64. BK=64, 2 phases/K-tile. Requires K >= 128, M=8192.
// Proven 620 TF on L3 (R6: 55.5us, FETCH minimal). R5's counted-lgkm ping-pong
// regressed (95us) — do not reintroduce.
// Tri-buffer: tile t read from buf[t%3]; stage targets buf[(t+2)%3] (3 loads/phase).
// vmcnt(6) once per K-tile: tile t+1's loads drain while t+2's stay in flight.
// Grid: linear nwg = 32*NBN; x=i&7, q=(i>>3)&3, bm=x+8q, bn=i>>5 -> the blocks
// sharing an A-panel (same bm) land on ONE XCD -> A fetched from HBM once.
// MODE 1: bias+relu -> bf16 (ldob)                              (L2)
// MODE 2: bias+tanh -> bf16 (ldob) + fp32 (ldof)                (L3)
// MODE 3: bias+relu -> fp32 split to d_out regions 0/1          (L4)
template<int MODE>
__launch_bounds__(512, 1)
__global__ void gemm256(const unsigned short* __restrict__ A,
                        const unsigned short* __restrict__ Bt,
                        int K, const float* __restrict__ bias,
                        unsigned short* __restrict__ outB, int ldob,
                        float* __restrict__ outF, int ldof) {
    constexpr int ABUF = 256 * 64;           // ushorts (32 KB)
    constexpr int BBUF = 128 * 64;           // ushorts (16 KB)
    constexpr int BUFE = ABUF + BBUF;        // 48 KB
    __shared__ alignas(16) unsigned short smem[3 * BUFE];   // 144 KB

    const int tid  = threadIdx.x;
    const int wave = tid >> 6;
    const int lane = tid & 63;
    const int i  = blockIdx.x;
    const int bm = (i & 7) + 8 * ((i >> 3) & 3);   // same-bm group -> same XCD
    const int bn = i >> 5;
    const int wm = wave >> 1, wn = wave & 1;
    const int lr = lane >> 4;
    const int lc = lane & 15;
    const int sw = lc & 7;
    const int nt = K >> 6;

    f32x4 acc[4][4] = {};

    long aoff[4], boff[2];
    #pragma unroll
    for (int j = 0; j < 4; ++j) {
        const int c   = tid + j * 512;
        const int row = c >> 3;
        const int kg  = (c & 7) ^ (row & 7);
        aoff[j] = (long)(bm * 256 + row) * K + kg * 8;
    }
    #pragma unroll
    for (int j = 0; j < 2; ++j) {
        const int c   = tid + j * 512;
        const int row = c >> 3;
        const int kg  = (c & 7) ^ (row & 7);
        boff[j] = (long)(bn * 128 + row) * K + kg * 8;
    }

    auto stageA2 = [&](int buf, int k0, int jlo) {   // 2 A loads
        char* base = (char*)(smem + buf * BUFE);
        load_lds16(A + aoff[jlo]     + k0, base + jlo       * 8192 + wave * 1024);
        load_lds16(A + aoff[jlo + 1] + k0, base + (jlo + 1) * 8192 + wave * 1024);
    };
    auto stageB1 = [&](int buf, int k0, int j) {     // 1 B load
        char* base = (char*)(smem + buf * BUFE) + ABUF * 2;
        load_lds16(Bt + boff[j] + k0, base + j * 8192 + wave * 1024);
    };
    auto dsA = [&](int buf, int kh, bf16x8* af) {
        const unsigned short* sA = smem + buf * BUFE;
        const int ch = (kh * 4 + lr) ^ sw;
        #pragma unroll
        for (int m = 0; m < 4; ++m)
            af[m] = *(const bf16x8*)(sA + (wm * 64 + m * 16 + lc) * 64 + ch * 8);
    };
    auto dsB = [&](int buf, int kh, bf16x8* bf) {
        const unsigned short* sB = smem + buf * BUFE + ABUF;
        const int ch = (kh * 4 + lr) ^ sw;
        #pragma unroll
        for (int n = 0; n < 4; ++n)
            bf[n] = *(const bf16x8*)(sB + (wn * 64 + n * 16 + lc) * 64 + ch * 8);
    };

    // prologue: stage tiles 0 and 1
    stageA2(0, 0, 0); stageA2(0, 0, 2); stageB1(0, 0, 0); stageB1(0, 0, 1);
    if (nt > 1) {
        stageA2(1, 64, 0); stageA2(1, 64, 2); stageB1(1, 64, 0); stageB1(1, 64, 1);
        asm volatile("s_waitcnt vmcnt(6)" ::: "memory");   // tile 0 landed
    } else {
        asm volatile("s_waitcnt vmcnt(0)" ::: "memory");
    }
    __builtin_amdgcn_s_barrier();

    int cur = 0;
    for (int t = 0; t < nt; ++t) {
        const int  k2   = (t + 2) << 6;
        const bool st   = (t + 2) < nt;
        const int  nbuf = (cur >= 1) ? cur - 1 : cur + 2;   // (t+2)%3

        bf16x8 af[4], bf[4];

        // ---- phase 0 (kh=0) ----
        if (st) { stageA2(nbuf, k2, 0); stageB1(nbuf, k2, 0); }
        dsA(cur, 0, af); dsB(cur, 0, bf);
        __builtin_amdgcn_s_barrier();
        asm volatile("s_waitcnt lgkmcnt(0)" ::: "memory");
        __builtin_amdgcn_sched_barrier(0);
        __builtin_amdgcn_s_setprio(1);
        #pragma unroll
        for (int m = 0; m < 4; ++m)
            #pragma unroll
            for (int n = 0; n < 4; ++n)
                acc[m][n] = __builtin_amdgcn_mfma_f32_16x16x32_bf16(af[m], bf[n], acc[m][n], 0, 0, 0);
        __builtin_amdgcn_s_setprio(0);
        __builtin_amdgcn_s_barrier();

        // ---- phase 1 (kh=1) ----
        if (st) { stageA2(nbuf, k2, 2); stageB1(nbuf, k2, 1); }
        dsA(cur, 1, af); dsB(cur, 1, bf);
        if (t + 1 < nt) {
            if (st) asm volatile("s_waitcnt vmcnt(6)" ::: "memory");  // tile t+1 landed
            else    asm volatile("s_waitcnt vmcnt(0)" ::: "memory");  // tail drain
        }
        __builtin_amdgcn_s_barrier();
        asm volatile("s_waitcnt lgkmcnt(0)" ::: "memory");
        __builtin_amdgcn_sched_barrier(0);
        __builtin_amdgcn_s_setprio(1);
        #pragma unroll
        for (int m = 0; m < 4; ++m)
            #pragma unroll
            for (int n = 0; n < 4; ++n)
                acc[m][n] = __builtin_amdgcn_mfma_f32_16x16x32_bf16(af[m], bf[n], acc[m][n], 0, 0, 0);
        __builtin_amdgcn_s_setprio(0);
        __builtin_amdgcn_s_barrier();

        cur = (cur == 2) ? 0 : cur + 1;
    }

    // ---- epilogue: bias + activation in registers ----
    #pragma unroll
    for (int n = 0; n < 4; ++n) {
        const float bv = bias[bn * 128 + wn * 64 + n * 16 + lc];
        #pragma unroll
        for (int m = 0; m < 4; ++m)
            #pragma unroll
            for (int r = 0; r < 4; ++r) {
                float v = acc[m][n][r] + bv;
                if constexpr (MODE == 2) v = tanhf(v);
                else                     v = fmaxf(v, 0.f);
                acc[m][n][r] = v;
            }
    }

    // ---- bf16 output (MODE 1,2): 256x128 tile via LDS (64 KB) ----
    if constexpr (MODE <= 2) {
        unsigned short* Cb = smem;
        __syncthreads();
        #pragma unroll
        for (int m = 0; m < 4; ++m)
            #pragma unroll
            for (int n = 0; n < 4; ++n)
                #pragma unroll
                for (int r = 0; r < 4; ++r)
                    Cb[(wm * 64 + m * 16 + lr * 4 + r) * 128 + wn * 64 + n * 16 + lc] =
                        f2bf(acc[m][n][r]);
        __syncthreads();
        #pragma unroll
        for (int tch = 0; tch < 8; ++tch) {
            const int chunk = tch * 512 + tid;
            const int row = chunk >> 4;       // 16 chunks of 16B per row
            const int c8  = chunk & 15;
            ushort8 v = *(ushort8*)(Cb + row * 128 + c8 * 8);
            *(ushort8*)(outB + (long)(bm * 256 + row) * ldob + bn * 128 + c8 * 8) = v;
        }
    }

    // ---- fp32 output (MODE 2,3): 256x128 tile via LDS (128 KB, one pass) ----
    if constexpr (MODE >= 2) {
        float* Cf = (float*)smem;
        __syncthreads();
        #pragma unroll
        for (int m = 0; m < 4; ++m)
            #pragma unroll
            for (int n = 0; n < 4; ++n)
                #pragma unroll
                for (int r = 0; r < 4; ++r)
                    Cf[(wm * 64 + m * 16 + lr * 4 + r) * 128 + wn * 64 + n * 16 + lc] =
                        acc[m][n][r];
        __syncthreads();
        #pragma unroll
        for (int tch = 0; tch < 16; ++tch) {
            const int chunk = tch * 512 + tid;
            const int row = chunk >> 5;       // 32 f32x4 per row
            const int c4  = chunk & 31;
            f32x4 v = *(f32x4*)(Cf + row * 128 + c4 * 4);
            const long grow = bm * 256 + row;
            if constexpr (MODE == 2) {
                *(f32x4*)(outF + grow * ldof + bn * 128 + c4 * 4) = v;
            } else {
                // 128-col tiles never straddle the OUT/O2C boundary (128 | 512)
                if (bn < 4)
                    *(f32x4*)(outF + grow * OUT_D + bn * 128 + c4 * 4) = v;
                else
                    *(f32x4*)(outF + (long)B_ROWS * OUT_D + grow * O2C_D
                              + (bn - 4) * 128 + c4 * 4) = v;
            }
        }
    }
}

// ---------------- launch ----------------
extern "C" void kernel_launch(void* const* d_in, const int* in_sizes, int n_in,
                              void* d_out, int out_size, void* d_ws, size_t ws_size,
                              hipStream_t stream) {
    const float* inputs = (const float*)d_in[0];
    const float* center = (const float*)d_in[1];
    const float* mstate = (const float*)d_in[2];
    const float* W_read = (const float*)d_in[3];
    const float* W_pre  = (const float*)d_in[4];
    const float* b_pre  = (const float*)d_in[5];
    const float* Wx     = (const float*)d_in[6];
    const float* Wh     = (const float*)d_in[7];
    const float* b_rnn  = (const float*)d_in[8];
    const float* W_post = (const float*)d_in[9];
    const float* b_post = (const float*)d_in[10];
    float* out = (float*)d_out;

    char* ws = (char*)d_ws;
    float* partials = (float*)ws;                                  // 128 floats
    unsigned short* WreadT = (unsigned short*)(ws + 1024);         // 256 x 512
    unsigned short* WpreT  = WreadT + 256 * 512;                   // 1024 x 768
    unsigned short* WxhT   = WpreT  + 1024 * 768;                  // 1024 x 2048
    unsigned short* WpostT = WxhT   + (long)1024 * 2048;           // 768 x 1024
    unsigned short* csB    = WpostT + 768 * 1024;                  // 8192 x 512
    unsigned short* miB    = csB + (long)B_ROWS * 512;             // 8192 x 768  [inputs | ctx]
    unsigned short* rnB    = miB + (long)B_ROWS * MIN_D;           // 8192 x 2048 [rnn_in | ms]
    unsigned short* hB     = rnB + (long)B_ROWS * 2048;            // 8192 x 1024

    prep_all<<<10176, 256, 0, stream>>>(W_read, partials,
                                        W_pre, Wx, Wh, W_post,
                                        WpreT, WxhT, WpostT, WreadT,
                                        center, inputs, mstate, csB, miB, rnB);

    // L1: context = (cs @ W_read) * clipscale -> miB cols [512..767]
    gemm_bt<0, 64><<<dim3(64, 4), 256, 0, stream>>>(csB, WreadT, 512, partials,
                                                    miB + 512, MIN_D, nullptr, 0);
    // L2: rnn_in = relu(mi @ W_pre + b_pre) -> rnB cols [0..1023]  (256 blocks, 1/CU)
    gemm256<1><<<256, 512, 0, stream>>>(miB, WpreT, 768, b_pre,
                                        rnB, 2048, nullptr, 0);
    // L3: h = tanh([rnn_in|ms] @ [Wx;Wh] + b_rnn) -> hB (bf16) + d_out region 2 (fp32)
    gemm256<2><<<256, 512, 0, stream>>>(rnB, WxhT, 2048, b_rnn,
                                        hB, RNN_D, out + (long)B_ROWS * TOT_D, RNN_D);
    // L4: module_output = relu(h @ W_post + b_post) -> fp32 d_out regions 0/1  (192 blocks)
    gemm256<3><<<192, 512, 0, stream>>>(hB, WpostT, 1024, b_post,
                                        nullptr, 0, out, 0);
}

// Round 8
// 237.577 us; speedup vs baseline: 1.0306x; 1.0306x over previous
//
#include <hip/hip_runtime.h>

// ---------------- types ----------------
typedef __bf16 bf16x8 __attribute__((ext_vector_type(8)));
typedef float  f32x4  __attribute__((ext_vector_type(4)));
typedef unsigned short ushort8 __attribute__((ext_vector_type(8)));

#define B_ROWS 8192
#define OUT_D  512
#define O2C_D  256
#define TOT_D  768
#define MIN_D  768
#define RNN_D  1024

__device__ __forceinline__ unsigned short f2bf(float f) {
    unsigned int u = __builtin_bit_cast(unsigned int, f);
    u = (u + 0x7fff + ((u >> 16) & 1)) >> 16;   // RNE
    return (unsigned short)u;
}

__device__ __forceinline__ void load_lds16(const void* g, void* l) {
    __builtin_amdgcn_global_load_lds(
        (const __attribute__((address_space(1))) unsigned int*)g,
        (__attribute__((address_space(3))) unsigned int*)l, 16, 0, 0);
}

// ---------------- fused prep kernel ----------------
// blockIdx segments: [0,128) reduce_sq partials; [128,1984) weight cvt; [1984,10176) act cvt
__launch_bounds__(256)
__global__ void prep_all(const float* __restrict__ Wread, float* __restrict__ partials,
                         const float* __restrict__ Wpre, const float* __restrict__ Wx,
                         const float* __restrict__ Wh,  const float* __restrict__ Wpost,
                         unsigned short* __restrict__ WpreT, unsigned short* __restrict__ WxhT,
                         unsigned short* __restrict__ WpostT, unsigned short* __restrict__ WreadT,
                         const float* __restrict__ center, const float* __restrict__ inputs,
                         const float* __restrict__ mstate,
                         unsigned short* __restrict__ csB, unsigned short* __restrict__ miB,
                         unsigned short* __restrict__ rnB) {
    const int bid = blockIdx.x;
    const int tid = threadIdx.x;
    if (bid < 128) {
        __shared__ float red[4];
        const float* p = Wread + bid * 1024 + tid * 4;
        f32x4 v = *(const f32x4*)p;
        float s = v[0]*v[0] + v[1]*v[1] + v[2]*v[2] + v[3]*v[3];
        #pragma unroll
        for (int off = 32; off > 0; off >>= 1) s += __shfl_down(s, off, 64);
        if ((tid & 63) == 0) red[tid >> 6] = s;
        __syncthreads();
        if (tid == 0) partials[bid] = red[0] + red[1] + red[2] + red[3];
        return;
    }
    if (bid < 1984) {
        int g = (bid - 128) * 256 + tid;
        const float* W; unsigned short* out; int N, ostride;
        if (g < 98304)        { W = Wpre;  out = WpreT;        N = 1024; ostride = 768;  }
        else if (g < 229376)  { g -= 98304;  W = Wx;    out = WxhT;        N = 1024; ostride = 2048; }
        else if (g < 360448)  { g -= 229376; W = Wh;    out = WxhT + 1024; N = 1024; ostride = 2048; }
        else if (g < 458752)  { g -= 360448; W = Wpost; out = WpostT;      N = 768;  ostride = 1024; }
        else                  { g -= 458752; W = Wread; out = WreadT;      N = 256;  ostride = 512;  }
        int n  = g % N;
        int kg = g / N;
        ushort8 o;
        #pragma unroll
        for (int j = 0; j < 8; ++j)
            o[j] = f2bf(W[(long)(kg * 8 + j) * N + n]);
        *(ushort8*)(out + (long)n * ostride + kg * 8) = o;
        return;
    }
    long g = (long)(bid - 1984) * 256 + tid;
    const float* src; unsigned short* dst; int logc, ostride;
    if (g < 524288)       { src = center; dst = csB;        logc = 9;  ostride = 512;  }
    else if (g < 1048576) { g -= 524288;  src = inputs; dst = miB;        logc = 9;  ostride = 768;  }
    else                  { g -= 1048576; src = mstate; dst = rnB + 1024; logc = 10; ostride = 2048; }
    long e = g * 8;
    long row = e >> logc;
    int  col = (int)(e & ((1 << logc) - 1));
    f32x4 v0 = *(const f32x4*)(src + e);
    f32x4 v1 = *(const f32x4*)(src + e + 4);
    ushort8 o;
    o[0] = f2bf(v0[0]); o[1] = f2bf(v0[1]); o[2] = f2bf(v0[2]); o[3] = f2bf(v0[3]);
    o[4] = f2bf(v1[0]); o[5] = f2bf(v1[1]); o[6] = f2bf(v1[2]); o[7] = f2bf(v1[3]);
    *(ushort8*)(dst + row * (long)ostride + col) = o;
}

// ---------------- small GEMM (single-buffer, round-0 proven) — used for L1 ----------------
// BM=128, BNT=64, BK=64. 4 waves. Conflict-free swizzle (verified r2/r6).
// MODE 0: *clipscale (bias = 128 partials of sum(W_read^2)) -> bf16
template<int MODE, int BNT>
__launch_bounds__(256, 4)
__global__ void gemm_bt(const unsigned short* __restrict__ A,
                        const unsigned short* __restrict__ Bt,
                        int K, const float* __restrict__ bias,
                        unsigned short* __restrict__ outB, int ldob,
                        float* __restrict__ outF, int ldof) {
    constexpr int U   = BNT / 32;
    constexpr int BJ  = BNT / 32;
    __shared__ alignas(16) unsigned short smem[128 * 64 + BNT * 64];
    unsigned short* sA = smem;
    unsigned short* sB = smem + 128 * 64;

    const int tid  = threadIdx.x;
    const int wave = tid >> 6;
    const int lane = tid & 63;
    const int bm = blockIdx.x, bn = blockIdx.y;
    const int wm = wave & 1, wn = wave >> 1;
    const int lr = lane >> 4;
    const int lc = lane & 15;
    const int sw = lc & 7;

    f32x4 acc[4][U] = {};

    long aoff[4], boff[BJ];
    #pragma unroll
    for (int j = 0; j < 4; ++j) {
        const int c   = tid + j * 256;
        const int row = c >> 3;
        const int kg  = (c & 7) ^ (row & 7);
        aoff[j] = (long)(bm * 128 + row) * K + kg * 8;
    }
    #pragma unroll
    for (int j = 0; j < BJ; ++j) {
        const int c   = tid + j * 256;
        const int row = c >> 3;
        const int kg  = (c & 7) ^ (row & 7);
        boff[j] = (long)(bn * BNT + row) * K + kg * 8;
    }

    for (int k0 = 0; k0 < K; k0 += 64) {
        #pragma unroll
        for (int j = 0; j < 4; ++j)
            load_lds16(A + aoff[j] + k0, (char*)sA + j * 4096 + wave * 1024);
        #pragma unroll
        for (int j = 0; j < BJ; ++j)
            load_lds16(Bt + boff[j] + k0, (char*)sB + j * 4096 + wave * 1024);
        __syncthreads();

        #pragma unroll
        for (int kh = 0; kh < 2; ++kh) {
            const int ch = (kh * 4 + lr) ^ sw;
            bf16x8 af[4], bfr[U];
            #pragma unroll
            for (int t = 0; t < 4; ++t)
                af[t] = *(const bf16x8*)(sA + (wm * 64 + t * 16 + lc) * 64 + ch * 8);
            #pragma unroll
            for (int u = 0; u < U; ++u)
                bfr[u] = *(const bf16x8*)(sB + (wn * (BNT / 2) + u * 16 + lc) * 64 + ch * 8);
            #pragma unroll
            for (int i = 0; i < 4; ++i)
                #pragma unroll
                for (int u = 0; u < U; ++u)
                    acc[i][u] = __builtin_amdgcn_mfma_f32_16x16x32_bf16(af[i], bfr[u], acc[i][u], 0, 0, 0);
        }
        __syncthreads();
    }

    float sc = 1.f;
    if constexpr (MODE == 0) {
        float s = 0.f;
        for (int i = 0; i < 128; ++i) s += bias[i];
        sc = 1.f / fmaxf(sqrtf(s), 1.f);
    }
    #pragma unroll
    for (int u = 0; u < U; ++u) {
        float bv = 0.f;
        if constexpr (MODE != 0) bv = bias[bn * BNT + wn * (BNT / 2) + u * 16 + lc];
        #pragma unroll
        for (int tm = 0; tm < 4; ++tm)
            #pragma unroll
            for (int r = 0; r < 4; ++r) {
                float v = acc[tm][u][r];
                if constexpr (MODE == 0) v *= sc;
                else v += bv;
                if constexpr (MODE == 1 || MODE == 3) v = fmaxf(v, 0.f);
                acc[tm][u][r] = v;
            }
    }

    const int ctcol = wn * (BNT / 2);

    if constexpr (MODE <= 2) {
        unsigned short* Cb = smem;
        #pragma unroll
        for (int u = 0; u < U; ++u)
            #pragma unroll
            for (int tm = 0; tm < 4; ++tm)
                #pragma unroll
                for (int r = 0; r < 4; ++r)
                    Cb[(wm * 64 + tm * 16 + lr * 4 + r) * BNT + ctcol + u * 16 + lc] =
                        f2bf(acc[tm][u][r]);
        __syncthreads();
        constexpr int RC = BNT / 8;
        constexpr int CPT = 128 * RC / 256;
        #pragma unroll
        for (int t = 0; t < CPT; ++t) {
            const int chunk = t * 256 + tid;
            const int row = chunk / RC;
            const int c8  = chunk % RC;
            ushort8 val = *(ushort8*)(Cb + row * BNT + c8 * 8);
            *(ushort8*)(outB + (long)(bm * 128 + row) * ldob + bn * BNT + c8 * 8) = val;
        }
    }

    if constexpr (MODE == 3) {
        float* Cf = (float*)smem;
        #pragma unroll
        for (int h = 0; h < 2; ++h) {
            __syncthreads();
            if (wm == h) {
                #pragma unroll
                for (int u = 0; u < U; ++u)
                    #pragma unroll
                    for (int tm = 0; tm < 4; ++tm)
                        #pragma unroll
                        for (int r = 0; r < 4; ++r)
                            Cf[(tm * 16 + lr * 4 + r) * BNT + ctcol + u * 16 + lc] =
                                acc[tm][u][r];
            }
            __syncthreads();
            constexpr int RCF = BNT / 4;
            constexpr int CPTF = 64 * RCF / 256;
            #pragma unroll
            for (int t = 0; t < CPTF; ++t) {
                const int chunk = t * 256 + tid;
                const int row = chunk / RCF;
                const int c4  = chunk % RCF;
                f32x4 val = *(f32x4*)(Cf + row * BNT + c4 * 4);
                const long grow = bm * 128 + h * 64 + row;
                if (bn * BNT < OUT_D)
                    *(f32x4*)(outF + grow * OUT_D + bn * BNT + c4 * 4) = val;
                else
                    *(f32x4*)(outF + (long)B_ROWS * OUT_D + grow * O2C_D
                              + (bn * BNT - OUT_D) + c4 * 4) = val;
            }
        }
    }
}

// ---------------- big GEMM: 256x128, tri-buffer, ONE barrier per K-tile ----------------
// 8 waves (4M x 2N), per-wave 64x64. BK=64. Requires K >= 128, M % 256 == 0.
// R7 lesson: the R4 schedule's 4 barriers/K-tile were ~65% of K-tile time
// (LDS ~1400cy + MFMA ~1230cy overlap-floor ~0.6us vs observed 1.7us @ 1 blk/CU).
// This is the catalog T3-minimum: per K-tile
//   stage6(t+2) -> 16 ds_read -> lgkmcnt(0)+sched_barrier -> 32 MFMA
//   -> vmcnt(6) -> s_barrier            (ONE barrier, counted vmcnt never 0)
// Hazards: stage at t writes buf[(t+2)%3]==buf[(t-1)%3], whose last reads drained
// at iter t-1's lgkmcnt(0) BEFORE that iter's barrier -> no WAR. vmcnt(6) leaves
// tile t+2's 6 loads in flight, drains t+1 -> visible after barrier. Tail vmcnt(0)
// at t=nt-2. (NOT the R5 failure: no counted lgkm, no cross-tile frag ping-pong.)
// Grid: linear nwg = 32*NBN; bm=(i&7)+8*((i>>3)&3), bn=i>>5 -> blocks sharing an
// A-panel land on ONE XCD -> A fetched from HBM once (R5/R6 proven, FETCH 33MB).
// MODE 1: bias+relu -> bf16 (ldob)                              (L2)
// MODE 2: bias+tanh -> bf16 (ldob) + fp32 (ldof)                (L3)
// MODE 3: bias+relu -> fp32 split to d_out regions 0/1          (L4)
template<int MODE>
__launch_bounds__(512, 1)
__global__ void gemm256(const unsigned short* __restrict__ A,
                        const unsigned short* __restrict__ Bt,
                        int K, const float* __restrict__ bias,
                        unsigned short* __restrict__ outB, int ldob,
                        float* __restrict__ outF, int ldof) {
    constexpr int ABUF = 256 * 64;           // ushorts (32 KB)
    constexpr int BBUF = 128 * 64;           // ushorts (16 KB)
    constexpr int BUFE = ABUF + BBUF;        // 48 KB
    __shared__ alignas(16) unsigned short smem[3 * BUFE];   // 144 KB

    const int tid  = threadIdx.x;
    const int wave = tid >> 6;
    const int lane = tid & 63;
    const int i  = blockIdx.x;
    const int bm = (i & 7) + 8 * ((i >> 3) & 3);   // same-bm group -> same XCD
    const int bn = i >> 5;
    const int wm = wave >> 1, wn = wave & 1;
    const int lr = lane >> 4;
    const int lc = lane & 15;
    const int sw = lc & 7;
    const int nt = K >> 6;

    f32x4 acc[4][4] = {};

    long aoff[4], boff[2];
    #pragma unroll
    for (int j = 0; j < 4; ++j) {
        const int c   = tid + j * 512;
        const int row = c >> 3;
        const int kg  = (c & 7) ^ (row & 7);
        aoff[j] = (long)(bm * 256 + row) * K + kg * 8;
    }
    #pragma unroll
    for (int j = 0; j < 2; ++j) {
        const int c   = tid + j * 512;
        const int row = c >> 3;
        const int kg  = (c & 7) ^ (row & 7);
        boff[j] = (long)(bn * 128 + row) * K + kg * 8;
    }

    auto stage6 = [&](int buf, int k0) {     // all 6 loads of one K-tile
        char* base = (char*)(smem + buf * BUFE);
        #pragma unroll
        for (int j = 0; j < 4; ++j)
            load_lds16(A + aoff[j] + k0, base + j * 8192 + wave * 1024);
        char* bbase = base + ABUF * 2;
        #pragma unroll
        for (int j = 0; j < 2; ++j)
            load_lds16(Bt + boff[j] + k0, bbase + j * 8192 + wave * 1024);
    };
    auto dsA = [&](int buf, int kh, bf16x8* af) {
        const unsigned short* sA = smem + buf * BUFE;
        const int ch = (kh * 4 + lr) ^ sw;
        #pragma unroll
        for (int m = 0; m < 4; ++m)
            af[m] = *(const bf16x8*)(sA + (wm * 64 + m * 16 + lc) * 64 + ch * 8);
    };
    auto dsB = [&](int buf, int kh, bf16x8* bf) {
        const unsigned short* sB = smem + buf * BUFE + ABUF;
        const int ch = (kh * 4 + lr) ^ sw;
        #pragma unroll
        for (int n = 0; n < 4; ++n)
            bf[n] = *(const bf16x8*)(sB + (wn * 64 + n * 16 + lc) * 64 + ch * 8);
    };

    // prologue: stage tiles 0 and 1; make tile 0 visible
    stage6(0, 0);
    if (nt > 1) {
        stage6(1, 64);
        asm volatile("s_waitcnt vmcnt(6)" ::: "memory");   // tile 0 landed
    } else {
        asm volatile("s_waitcnt vmcnt(0)" ::: "memory");
    }
    __builtin_amdgcn_s_barrier();

    int cur = 0;
    for (int t = 0; t < nt; ++t) {
        const bool st   = (t + 2) < nt;
        const int  nbuf = (cur >= 1) ? cur - 1 : cur + 2;   // (t+2)%3

        if (st) stage6(nbuf, (t + 2) << 6);

        bf16x8 af0[4], bf0[4], af1[4], bf1[4];
        dsA(cur, 0, af0); dsB(cur, 0, bf0);
        dsA(cur, 1, af1); dsB(cur, 1, bf1);
        asm volatile("s_waitcnt lgkmcnt(0)" ::: "memory");
        __builtin_amdgcn_sched_barrier(0);
        __builtin_amdgcn_s_setprio(1);
        #pragma unroll
        for (int m = 0; m < 4; ++m)
            #pragma unroll
            for (int n = 0; n < 4; ++n)
                acc[m][n] = __builtin_amdgcn_mfma_f32_16x16x32_bf16(af0[m], bf0[n], acc[m][n], 0, 0, 0);
        #pragma unroll
        for (int m = 0; m < 4; ++m)
            #pragma unroll
            for (int n = 0; n < 4; ++n)
                acc[m][n] = __builtin_amdgcn_mfma_f32_16x16x32_bf16(af1[m], bf1[n], acc[m][n], 0, 0, 0);
        __builtin_amdgcn_s_setprio(0);

        if (t + 1 < nt) {
            if (st) asm volatile("s_waitcnt vmcnt(6)" ::: "memory");  // tile t+1 landed
            else    asm volatile("s_waitcnt vmcnt(0)" ::: "memory");  // tail drain
        }
        __builtin_amdgcn_s_barrier();   // t+1 visible; buf[(t+2)%3] write-safe next iter

        cur = (cur == 2) ? 0 : cur + 1;
    }

    // ---- epilogue: bias + activation in registers ----
    #pragma unroll
    for (int n = 0; n < 4; ++n) {
        const float bv = bias[bn * 128 + wn * 64 + n * 16 + lc];
        #pragma unroll
        for (int m = 0; m < 4; ++m)
            #pragma unroll
            for (int r = 0; r < 4; ++r) {
                float v = acc[m][n][r] + bv;
                if constexpr (MODE == 2) v = tanhf(v);
                else                     v = fmaxf(v, 0.f);
                acc[m][n][r] = v;
            }
    }

    // ---- bf16 output (MODE 1,2): 256x128 tile via LDS (64 KB) ----
    if constexpr (MODE <= 2) {
        unsigned short* Cb = smem;
        __syncthreads();
        #pragma unroll
        for (int m = 0; m < 4; ++m)
            #pragma unroll
            for (int n = 0; n < 4; ++n)
                #pragma unroll
                for (int r = 0; r < 4; ++r)
                    Cb[(wm * 64 + m * 16 + lr * 4 + r) * 128 + wn * 64 + n * 16 + lc] =
                        f2bf(acc[m][n][r]);
        __syncthreads();
        #pragma unroll
        for (int tch = 0; tch < 8; ++tch) {
            const int chunk = tch * 512 + tid;
            const int row = chunk >> 4;       // 16 chunks of 16B per row
            const int c8  = chunk & 15;
            ushort8 v = *(ushort8*)(Cb + row * 128 + c8 * 8);
            *(ushort8*)(outB + (long)(bm * 256 + row) * ldob + bn * 128 + c8 * 8) = v;
        }
    }

    // ---- fp32 output (MODE 2,3): 256x128 tile via LDS (128 KB, one pass) ----
    if constexpr (MODE >= 2) {
        float* Cf = (float*)smem;
        __syncthreads();
        #pragma unroll
        for (int m = 0; m < 4; ++m)
            #pragma unroll
            for (int n = 0; n < 4; ++n)
                #pragma unroll
                for (int r = 0; r < 4; ++r)
                    Cf[(wm * 64 + m * 16 + lr * 4 + r) * 128 + wn * 64 + n * 16 + lc] =
                        acc[m][n][r];
        __syncthreads();
        #pragma unroll
        for (int tch = 0; tch < 16; ++tch) {
            const int chunk = tch * 512 + tid;
            const int row = chunk >> 5;       // 32 f32x4 per row
            const int c4  = chunk & 31;
            f32x4 v = *(f32x4*)(Cf + row * 128 + c4 * 4);
            const long grow = bm * 256 + row;
            if constexpr (MODE == 2) {
                *(f32x4*)(outF + grow * ldof + bn * 128 + c4 * 4) = v;
            } else {
                // 128-col tiles never straddle the OUT/O2C boundary (128 | 512)
                if (bn < 4)
                    *(f32x4*)(outF + grow * OUT_D + bn * 128 + c4 * 4) = v;
                else
                    *(f32x4*)(outF + (long)B_ROWS * OUT_D + grow * O2C_D
                              + (bn - 4) * 128 + c4 * 4) = v;
            }
        }
    }
}

// ---------------- launch ----------------
extern "C" void kernel_launch(void* const* d_in, const int* in_sizes, int n_in,
                              void* d_out, int out_size, void* d_ws, size_t ws_size,
                              hipStream_t stream) {
    const float* inputs = (const float*)d_in[0];
    const float* center = (const float*)d_in[1];
    const float* mstate = (const float*)d_in[2];
    const float* W_read = (const float*)d_in[3];
    const float* W_pre  = (const float*)d_in[4];
    const float* b_pre  = (const float*)d_in[5];
    const float* Wx     = (const float*)d_in[6];
    const float* Wh     = (const float*)d_in[7];
    const float* b_rnn  = (const float*)d_in[8];
    const float* W_post = (const float*)d_in[9];
    const float* b_post = (const float*)d_in[10];
    float* out = (float*)d_out;

    char* ws = (char*)d_ws;
    float* partials = (float*)ws;                                  // 128 floats
    unsigned short* WreadT = (unsigned short*)(ws + 1024);         // 256 x 512
    unsigned short* WpreT  = WreadT + 256 * 512;                   // 1024 x 768
    unsigned short* WxhT   = WpreT  + 1024 * 768;                  // 1024 x 2048
    unsigned short* WpostT = WxhT   + (long)1024 * 2048;           // 768 x 1024
    unsigned short* csB    = WpostT + 768 * 1024;                  // 8192 x 512
    unsigned short* miB    = csB + (long)B_ROWS * 512;             // 8192 x 768  [inputs | ctx]
    unsigned short* rnB    = miB + (long)B_ROWS * MIN_D;           // 8192 x 2048 [rnn_in | ms]
    unsigned short* hB     = rnB + (long)B_ROWS * 2048;            // 8192 x 1024

    prep_all<<<10176, 256, 0, stream>>>(W_read, partials,
                                        W_pre, Wx, Wh, W_post,
                                        WpreT, WxhT, WpostT, WreadT,
                                        center, inputs, mstate, csB, miB, rnB);

    // L1: context = (cs @ W_read) * clipscale -> miB cols [512..767]
    gemm_bt<0, 64><<<dim3(64, 4), 256, 0, stream>>>(csB, WreadT, 512, partials,
                                                    miB + 512, MIN_D, nullptr, 0);
    // L2: rnn_in = relu(mi @ W_pre + b_pre) -> rnB cols [0..1023]  (256 blocks, 1/CU)
    gemm256<1><<<256, 512, 0, stream>>>(miB, WpreT, 768, b_pre,
                                        rnB, 2048, nullptr, 0);
    // L3: h = tanh([rnn_in|ms] @ [Wx;Wh] + b_rnn) -> hB (bf16) + d_out region 2 (fp32)
    gemm256<2><<<256, 512, 0, stream>>>(rnB, WxhT, 2048, b_rnn,
                                        hB, RNN_D, out + (long)B_ROWS * TOT_D, RNN_D);
    // L4: module_output = relu(h @ W_post + b_post) -> fp32 d_out regions 0/1  (192 blocks)
    gemm256<3><<<192, 512, 0, stream>>>(hB, WpostT, 1024, b_post,
                                        nullptr, 0, out, 0);
}